// Round 27
// baseline (244.538 us; speedup 1.0000x reference)
//
#include <hip/hip_runtime.h>

#define NPTS 40000
#define NEDGE 1000000
#define BN_EPS 1e-5f

typedef short bf16x8 __attribute__((ext_vector_type(8)));
typedef float f32x4 __attribute__((ext_vector_type(4)));

__device__ __forceinline__ unsigned short f2bf(float x) {
    unsigned u = __float_as_uint(x);
    return (unsigned short)((u + 0x7FFFu + ((u >> 16) & 1u)) >> 16);  // RTN-even
}
__device__ __forceinline__ bf16x8 pack8(unsigned v0, unsigned v1, unsigned v2, unsigned v3,
                                        unsigned v4, unsigned v5, unsigned v6, unsigned v7) {
    uint4 u = make_uint4(v0 | (v1 << 16), v2 | (v3 << 16), v4 | (v5 << 16), v6 | (v7 << 16));
    return __builtin_bit_cast(bf16x8, u);
}

// ===========================================================================
// Edge geometry: validity + cell + corner weights (w00,w01,w10,w11).
// ===========================================================================
__device__ inline bool edge_geom(const float* rel_pos, const int* ws_ptr, int e,
                                 int& cell, float4& w4) {
    float ws = (float)ws_ptr[0];
    float inv_ws = 1.0f / ws;
    float ux = rel_pos[2 * e] * inv_ws;
    float uy = rel_pos[2 * e + 1] * inv_ws;
    float q = 1.0f - (ux * ux + uy * uy);
    if (!(q > 0.0f)) return false;
    float win = q * q * q;
    float gx = fminf(fmaxf((ux + 1.0f) * 1.5f, 0.0f), 3.0f);
    float gy = fminf(fmaxf((uy + 1.0f) * 1.5f, 0.0f), 3.0f);
    int ix = (int)floorf(gx); ix = ix < 0 ? 0 : (ix > 2 ? 2 : ix);
    int iy = (int)floorf(gy); iy = iy < 0 ? 0 : (iy > 2 ? 2 : iy);
    float fx = gx - (float)ix;
    float fy = gy - (float)iy;
    cell = ix * 4 + iy;
    float wx0 = (1.f - fx) * win, wx1 = fx * win;
    float wy0 = 1.f - fy, wy1 = fy;
    w4 = make_float4(wx0 * wy0, wx0 * wy1, wx1 * wy0, wx1 * wy1);
    return true;
}

// hist captures each edge's rank (atomicAdd return) so fill is atomic-free.
__global__ void hist_kernel(const float* __restrict__ rel_pos,
                            const int* __restrict__ receivers,
                            const int* __restrict__ ws_ptr,
                            int* __restrict__ cnt,
                            int* __restrict__ rank) {
    int base = blockIdx.x * 1024 + threadIdx.x;
#pragma unroll
    for (int i = 0; i < 4; ++i) {
        int e = base + i * 256;
        if (e >= NEDGE) continue;
        int cell; float4 w4;
        int r = -1;
        if (edge_geom(rel_pos, ws_ptr, e, cell, w4))
            r = atomicAdd(&cnt[receivers[e]], 1);
        rank[e] = r;
    }
}

// one block, 1024 threads: exclusive scan of 40000 counts -> rowptr[40001]
__global__ __launch_bounds__(1024) void scan_kernel(const int* __restrict__ cnt,
                                                    int* __restrict__ rowptr) {
    __shared__ int part[1024];
    int t = threadIdx.x;
    const int CHUNK = 40;
    int base = t * CHUNK;
    int s = 0;
    if (t < 1000)
        for (int i = 0; i < CHUNK; ++i) s += cnt[base + i];
    part[t] = s;
    __syncthreads();
    for (int off = 1; off < 1024; off <<= 1) {
        int v = (t >= off) ? part[t - off] : 0;
        __syncthreads();
        part[t] += v;
        __syncthreads();
    }
    int excl = (t == 0) ? 0 : part[t - 1];
    if (t < 1000) {
        int run = excl;
        for (int i = 0; i < CHUNK; ++i) { rowptr[base + i] = run; run += cnt[base + i]; }
        if (t == 999) rowptr[NPTS] = run;
    }
}

// Edge record 16B: {sender | cell<<16, bf16(w00)|bf16(w01)<<16,
//                   bf16(w10)|bf16(w11)<<16, 0}; atomic-free via rank[].
__global__ void fill_kernel(const float* __restrict__ rel_pos,
                            const int* __restrict__ receivers,
                            const int* __restrict__ senders,
                            const int* __restrict__ ws_ptr,
                            const int* __restrict__ rowptr,
                            const int* __restrict__ rank,
                            uint4* __restrict__ ec) {
    int base = blockIdx.x * 1024 + threadIdx.x;
#pragma unroll
    for (int i = 0; i < 4; ++i) {
        int e = base + i * 256;
        if (e >= NEDGE) continue;
        int r = rank[e];
        if (r < 0) continue;
        int cell; float4 w4;
        edge_geom(rel_pos, ws_ptr, e, cell, w4);   // valid by construction
        int pos = rowptr[receivers[e]] + r;
        unsigned meta = (unsigned)senders[e] | ((unsigned)cell << 16);
        unsigned wlo = (unsigned)f2bf(w4.x) | ((unsigned)f2bf(w4.y) << 16);
        unsigned whi = (unsigned)f2bf(w4.z) | ((unsigned)f2bf(w4.w) << 16);
        ec[pos] = make_uint4(meta, wlo, whi, 0u);
    }
}

// ===========================================================================
// Merged W repack into bf16 MFMA B-fragment layout.
// ===========================================================================
__global__ void pack_all_kernel(const float* __restrict__ W1, const float* __restrict__ W2,
                                const float* __restrict__ W3, const float* __restrict__ W4,
                                unsigned short* __restrict__ Wp1, unsigned short* __restrict__ Wp2,
                                unsigned short* __restrict__ Wp3, unsigned short* __restrict__ Wp4) {
    int idx = blockIdx.x * 256 + threadIdx.x;
    const float* W; unsigned short* Wp; int M, COUT, base;
    if (idx < 65536)       { W = W1; Wp = Wp1; M = 1024; COUT = 64; base = 0; }
    else if (idx < 98304)  { W = W2; Wp = Wp2; M = 1024; COUT = 32; base = 65536; }
    else if (idx < 131072) { W = W3; Wp = Wp3; M = 512;  COUT = 64; base = 98304; }
    else if (idx < 163840) { W = W4; Wp = Wp4; M = 1024; COUT = 32; base = 131072; }
    else return;
    int i = idx - base;
    int nKS = M / 32;
    int j = i & 7, l = (i >> 3) & 63, t = i >> 9;
    int ks = t % nKS, cb = t / nKS;
    int m = ks * 32 + (l >> 4) * 8 + j;
    int col = cb * 16 + (l & 15);
    Wp[i] = f2bf(W[(size_t)m * COUT + col]);
}

// bf16 concat(x,y) -> xab[N][64]
__global__ void build_xab_kernel(const float* __restrict__ x,
                                 const float* __restrict__ y,
                                 unsigned short* __restrict__ xab) {
    int t = blockIdx.x * blockDim.x + threadIdx.x;
    if (t >= NPTS * 64) return;
    int n = t >> 6, c = t & 63;
    xab[t] = f2bf((c < 32) ? x[n * 32 + c] : y[n * 32 + (c - 32)]);
}

// ===========================================================================
// Fused cconv layer, MFMA scatter + MFMA GEMM.
// RB=8 (r27): halves S_bf to 16.5KB; stage/Rred share a 2KB union ->
// ~18.6KB LDS -> 8 blocks/CU = 32 waves/CU (2x r24's occupancy; r24 was
// latency-bound at 32% occupancy, LDS-pinned). Phase 2 rows 8..15 are
// computed-and-discarded (A reads alias row&7; MFMA rows independent).
// Cost accepted: W L2 traffic doubles (2x blocks) -- revert if it dominates.
// ===========================================================================
template <int CIN, int COUT>
__global__ __launch_bounds__(256, 4) void fused_layer(const unsigned short* __restrict__ featb,
                                                      const uint4* __restrict__ ec,
                                                      const int* __restrict__ rowptr,
                                                      const unsigned short* __restrict__ Wp,
                                                      const float* __restrict__ a,
                                                      float* __restrict__ P,
                                                      float* __restrict__ part) {
    constexpr int RB = 8;             // receivers per block
    constexpr int M = 16 * CIN;
    constexpr int LDB = M + 8;
    constexpr int nKS = M / 32;
    constexpr int NCB = CIN / 16;
    constexpr int CT = COUT / 16;
    __shared__ short S_bf[RB * LDB];
    __shared__ char sh_union[2048];   // phase1: stage[4][32] uint4; phase2: Rred
    uint4(*stage)[32] = (uint4(*)[32])sh_union;
    float* Rred = (float*)sh_union;   // CT==2: [2][8][16] = 1KB

    int tid = threadIdx.x;
    int lane = tid & 63;
    int wave = tid >> 6;
    int col = lane & 15;
    int kgrp = lane >> 4;
    int rcx = col >> 2, rcy = col & 3;

    for (int r = 0; r < 2; ++r) {     // 2 receivers per wave
        int rloc = wave * 2 + r;
        int rglob = blockIdx.x * RB + rloc;
        int rs = rowptr[rglob];
        int deg = rowptr[rglob + 1] - rs;

        f32x4 acc[NCB];
#pragma unroll
        for (int cb = 0; cb < NCB; ++cb) acc[cb] = f32x4{0.f, 0.f, 0.f, 0.f};

        for (int c0 = 0; c0 < deg; c0 += 32) {
            if (lane < 32) {
                uint4 rec = (c0 + lane < deg) ? ec[rs + c0 + lane]
                                              : make_uint4(0u, 0u, 0u, 0u);
                stage[wave][lane] = rec;
            }
            unsigned aw[8];
            uint2 fv4[8];
            unsigned fv2[8];
#pragma unroll
            for (int j = 0; j < 8; ++j) {
                uint4 rec = stage[wave][kgrp * 8 + j];
                int cell = (int)(rec.x >> 16);
                int ix = cell >> 2, iy = cell & 3;
                unsigned pair = (rcx == ix) ? rec.y : rec.z;
                unsigned half = (rcy == iy) ? (pair & 0xFFFFu) : (pair >> 16);
                bool vx = (rcx == ix) || (rcx == ix + 1);
                bool vy = (rcy == iy) || (rcy == iy + 1);
                aw[j] = (vx && vy) ? half : 0u;
                int sb = (int)(rec.x & 0xFFFFu) * CIN + col * NCB;
                if constexpr (NCB == 4)
                    fv4[j] = *(const uint2*)&featb[sb];
                else
                    fv2[j] = *(const unsigned*)&featb[sb];
            }
            bf16x8 afrag = pack8(aw[0], aw[1], aw[2], aw[3], aw[4], aw[5], aw[6], aw[7]);
            if constexpr (NCB == 4) {
                bf16x8 b0 = pack8(fv4[0].x & 0xFFFFu, fv4[1].x & 0xFFFFu, fv4[2].x & 0xFFFFu,
                                  fv4[3].x & 0xFFFFu, fv4[4].x & 0xFFFFu, fv4[5].x & 0xFFFFu,
                                  fv4[6].x & 0xFFFFu, fv4[7].x & 0xFFFFu);
                bf16x8 b1 = pack8(fv4[0].x >> 16, fv4[1].x >> 16, fv4[2].x >> 16, fv4[3].x >> 16,
                                  fv4[4].x >> 16, fv4[5].x >> 16, fv4[6].x >> 16, fv4[7].x >> 16);
                bf16x8 b2 = pack8(fv4[0].y & 0xFFFFu, fv4[1].y & 0xFFFFu, fv4[2].y & 0xFFFFu,
                                  fv4[3].y & 0xFFFFu, fv4[4].y & 0xFFFFu, fv4[5].y & 0xFFFFu,
                                  fv4[6].y & 0xFFFFu, fv4[7].y & 0xFFFFu);
                bf16x8 b3 = pack8(fv4[0].y >> 16, fv4[1].y >> 16, fv4[2].y >> 16, fv4[3].y >> 16,
                                  fv4[4].y >> 16, fv4[5].y >> 16, fv4[6].y >> 16, fv4[7].y >> 16);
                acc[0] = __builtin_amdgcn_mfma_f32_16x16x32_bf16(afrag, b0, acc[0], 0, 0, 0);
                acc[1] = __builtin_amdgcn_mfma_f32_16x16x32_bf16(afrag, b1, acc[1], 0, 0, 0);
                acc[2] = __builtin_amdgcn_mfma_f32_16x16x32_bf16(afrag, b2, acc[2], 0, 0, 0);
                acc[3] = __builtin_amdgcn_mfma_f32_16x16x32_bf16(afrag, b3, acc[3], 0, 0, 0);
            } else {
                bf16x8 b0 = pack8(fv2[0] & 0xFFFFu, fv2[1] & 0xFFFFu, fv2[2] & 0xFFFFu,
                                  fv2[3] & 0xFFFFu, fv2[4] & 0xFFFFu, fv2[5] & 0xFFFFu,
                                  fv2[6] & 0xFFFFu, fv2[7] & 0xFFFFu);
                bf16x8 b1 = pack8(fv2[0] >> 16, fv2[1] >> 16, fv2[2] >> 16, fv2[3] >> 16,
                                  fv2[4] >> 16, fv2[5] >> 16, fv2[6] >> 16, fv2[7] >> 16);
                acc[0] = __builtin_amdgcn_mfma_f32_16x16x32_bf16(afrag, b0, acc[0], 0, 0, 0);
                acc[1] = __builtin_amdgcn_mfma_f32_16x16x32_bf16(afrag, b1, acc[1], 0, 0, 0);
            }
        }

        // epilogue: unpermute -> S_bf[cell][channel], channel = col*NCB + cb
        short* srow = &S_bf[rloc * LDB];
#pragma unroll
        for (int i = 0; i < 4; ++i) {
            if constexpr (NCB == 4) {
                unsigned lo = (unsigned)f2bf(acc[0][i]) | ((unsigned)f2bf(acc[1][i]) << 16);
                unsigned hi = (unsigned)f2bf(acc[2][i]) | ((unsigned)f2bf(acc[3][i]) << 16);
                *(uint2*)&srow[(kgrp * 4 + i) * CIN + col * 4] = make_uint2(lo, hi);
            } else {
                unsigned lo = (unsigned)f2bf(acc[0][i]) | ((unsigned)f2bf(acc[1][i]) << 16);
                *(unsigned*)&srow[(kgrp * 4 + i) * CIN + col * 2] = lo;
            }
        }
    }
    __syncthreads();

    // --- phase 2: MFMA GEMM over 8 valid rows (rows 8-15 discarded) ---
    int row16 = lane & 15;
    f32x4 c = {0.f, 0.f, 0.f, 0.f};
    int cb, ks0;
    constexpr int KS_PER = (CT == 4) ? nKS : nKS / 2;
    if constexpr (CT == 4) { cb = wave; ks0 = 0; }
    else { cb = wave & 1; ks0 = (wave >> 1) * KS_PER; }

    const short* abase = &S_bf[(row16 & 7) * LDB + kgrp * 8];  // alias rows 8-15
    const bf16x8* wfrag = (const bf16x8*)Wp;
    size_t wbase = (size_t)(cb * nKS + ks0) * 64 + lane;
#pragma unroll 8
    for (int kk = 0; kk < KS_PER; ++kk) {
        bf16x8 af = *(const bf16x8*)(abase + (size_t)(ks0 + kk) * 32);
        bf16x8 bf = wfrag[wbase + (size_t)kk * 64];
        c = __builtin_amdgcn_mfma_f32_16x16x32_bf16(af, bf, c, 0, 0, 0);
    }

    if constexpr (CT == 2) {
        if (wave >= 2) {
#pragma unroll
            for (int i = 0; i < 4; ++i) {
                int row = kgrp * 4 + i;
                if (row < 8) Rred[cb * 128 + row * 16 + row16] = c[i];
            }
        }
        __syncthreads();
        if (wave < 2) {
            float sp = 0.f, sq = 0.f;
#pragma unroll
            for (int i = 0; i < 4; ++i) {
                int row = kgrp * 4 + i;
                if (row < 8) {
                    int n = blockIdx.x * RB + row;
                    float v = a[n] * (c[i] + Rred[cb * 128 + row * 16 + row16]);
                    P[(size_t)n * COUT + cb * 16 + row16] = v;
                    sp += v; sq += v * v;
                }
            }
            sp += __shfl_xor(sp, 16); sp += __shfl_xor(sp, 32);
            sq += __shfl_xor(sq, 16); sq += __shfl_xor(sq, 32);
            if (kgrp == 0) {
                part[(size_t)blockIdx.x * 2 * COUT + cb * 16 + row16] = sp;
                part[(size_t)blockIdx.x * 2 * COUT + COUT + cb * 16 + row16] = sq;
            }
        }
    } else {
        float sp = 0.f, sq = 0.f;
#pragma unroll
        for (int i = 0; i < 4; ++i) {
            int row = kgrp * 4 + i;
            if (row < 8) {
                int n = blockIdx.x * RB + row;
                float v = a[n] * c[i];
                P[(size_t)n * COUT + cb * 16 + row16] = v;
                sp += v; sq += v * v;
            }
        }
        sp += __shfl_xor(sp, 16); sp += __shfl_xor(sp, 32);
        sq += __shfl_xor(sq, 16); sq += __shfl_xor(sq, 32);
        if (kgrp == 0) {
            part[(size_t)blockIdx.x * 2 * COUT + cb * 16 + row16] = sp;
            part[(size_t)blockIdx.x * 2 * COUT + COUT + cb * 16 + row16] = sq;
        }
    }
}

// ===========================================================================
// BN reduction (static trip counts; NB = NPTS/8 = 5000 partial rows).
// ===========================================================================
template <int COUT>
__global__ __launch_bounds__(256) void bn_mid_kernel(const float* __restrict__ part,
                                                     float* __restrict__ part2) {
    constexpr int C2 = 2 * COUT;
    constexpr int NG = 256 / C2;
    constexpr int NB = NPTS / 8;          // 5000
    constexpr int NRB = (NB + 63) / 64;   // 79
    __shared__ float ls[256];
    int tid = threadIdx.x;
    int d = tid % C2;
    int gi = tid / C2;
    int k0 = blockIdx.x * NRB;
    float s = 0.f;
#pragma unroll
    for (int j = 0; j < NRB / NG + 1; ++j) {
        int k = k0 + gi + j * NG;
        bool ok = (gi + j * NG < NRB) && (k < NB);
        s += ok ? part[(size_t)k * C2 + d] : 0.f;
    }
    ls[tid] = s;
    __syncthreads();
    if (gi == 0) {
        float tot = s;
#pragma unroll
        for (int g2 = 1; g2 < NG; ++g2) tot += ls[tid + g2 * C2];
        part2[(size_t)blockIdx.x * C2 + d] = tot;
    }
}

template <int COUT>
__global__ __launch_bounds__(1024) void bn_fin_kernel(const float* __restrict__ part2,
                                                      const float* __restrict__ g,
                                                      const float* __restrict__ b,
                                                      float* __restrict__ scb) {
    constexpr int C2 = 2 * COUT;
    constexpr int NG = 1024 / C2;
    __shared__ float ls[1024];
    int tid = threadIdx.x;
    int d = tid % C2;
    int gi = tid / C2;
    float s = 0.f;
#pragma unroll
    for (int j = 0; j < 64 / NG; ++j)
        s += part2[(size_t)(gi + j * NG) * C2 + d];
    ls[tid] = s;
    __syncthreads();
    if (tid < C2) {
        float tot = ls[tid];
#pragma unroll
        for (int g2 = 1; g2 < NG; ++g2) tot += ls[tid + g2 * C2];
        ls[tid] = tot;
    }
    __syncthreads();
    if (tid < COUT) {
        float sum = ls[tid], ssq = ls[COUT + tid];
        float mean = sum / (float)NPTS;
        float var = ssq / (float)NPTS - mean * mean;
        float inv = rsqrtf(var + BN_EPS);
        float scale = inv * g[tid];
        scb[tid] = scale;
        scb[COUT + tid] = b[tid] - mean * scale;
    }
}

// relu(bn(P)) -> bf16 feature buffer
template <int COUT>
__global__ void apply_relu_bf16_kernel(const float* __restrict__ P,
                                       const float* __restrict__ scb,
                                       unsigned short* __restrict__ fb) {
    int t = blockIdx.x * blockDim.x + threadIdx.x;
    if (t >= NPTS * COUT) return;
    int d = t % COUT;
    float v = P[t] * scb[d] + scb[COUT + d];
    fb[t] = f2bf(fmaxf(v, 0.0f));
}

// sigmoid-mix -> bf16 feature buffer
__global__ void apply_sigmix_bf16_kernel(const float* __restrict__ P,
                                         const float* __restrict__ scb,
                                         const float* __restrict__ x,
                                         const float* __restrict__ y,
                                         unsigned short* __restrict__ xob) {
    int t = blockIdx.x * blockDim.x + threadIdx.x;
    if (t >= NPTS * 32) return;
    int d = t & 31;
    float v = P[t] * scb[d] + scb[32 + d];
    float w = 1.0f / (1.0f + expf(-v));
    xob[t] = f2bf(2.0f * x[t] * w + 2.0f * y[t] * (1.0f - w));
}

// final sigmoid-mix -> f32 output
__global__ void apply_sigmix_kernel(const float* __restrict__ P,
                                    const float* __restrict__ scb,
                                    const float* __restrict__ x,
                                    const float* __restrict__ y,
                                    float* __restrict__ out) {
    int t = blockIdx.x * blockDim.x + threadIdx.x;
    if (t >= NPTS * 32) return;
    int d = t & 31;
    float v = P[t] * scb[d] + scb[32 + d];
    float w = 1.0f / (1.0f + expf(-v));
    out[t] = 2.0f * x[t] * w + 2.0f * y[t] * (1.0f - w);
}

extern "C" void kernel_launch(void* const* d_in, const int* in_sizes, int n_in,
                              void* d_out, int out_size, void* d_ws, size_t ws_size,
                              hipStream_t stream) {
    const float* x = (const float*)d_in[0];
    const float* y = (const float*)d_in[1];
    const int* senders = (const int*)d_in[2];
    const int* receivers = (const int*)d_in[3];
    const float* rel_pos = (const float*)d_in[4];
    const int* ws_ptr = (const int*)d_in[5];
    const float* a = (const float*)d_in[6];
    const float* W1 = (const float*)d_in[7];
    const float* W2 = (const float*)d_in[8];
    const float* W3 = (const float*)d_in[9];
    const float* W4 = (const float*)d_in[10];
    const float* g1 = (const float*)d_in[11];
    const float* b1 = (const float*)d_in[12];
    const float* g2 = (const float*)d_in[13];
    const float* b2 = (const float*)d_in[14];
    const float* g3 = (const float*)d_in[15];
    const float* b3 = (const float*)d_in[16];
    const float* g4 = (const float*)d_in[17];
    const float* b4 = (const float*)d_in[18];

    char* ws = (char*)d_ws;
    size_t off = 0;
    auto alloc = [&](size_t bytes) -> void* {
        void* p = ws + off;
        off += (bytes + 255) & ~(size_t)255;
        return p;
    };
    int* cnt = (int*)alloc((size_t)NPTS * sizeof(int));
    int* rowptr = (int*)alloc((size_t)(NPTS + 1) * sizeof(int));
    int* rank = (int*)alloc((size_t)NEDGE * sizeof(int));
    uint4* ec = (uint4*)alloc((size_t)(NEDGE + 4) * sizeof(uint4));
    unsigned short* xab = (unsigned short*)alloc((size_t)NPTS * 64 * 2);
    unsigned short* fb64 = (unsigned short*)alloc((size_t)NPTS * 64 * 2);
    unsigned short* xob = (unsigned short*)alloc((size_t)NPTS * 32 * 2);
    float* P1 = (float*)alloc((size_t)NPTS * 64 * sizeof(float));  // also P3
    float* P2 = (float*)alloc((size_t)NPTS * 32 * sizeof(float));  // also P4
    float* part = (float*)alloc((size_t)(NPTS / 8) * 128 * sizeof(float));
    float* part2 = (float*)alloc((size_t)64 * 128 * sizeof(float));
    float* scb = (float*)alloc(2 * 64 * sizeof(float));
    unsigned short* Wp1 = (unsigned short*)alloc((size_t)1024 * 64 * 2);
    unsigned short* Wp2 = (unsigned short*)alloc((size_t)1024 * 32 * 2);
    unsigned short* Wp3 = (unsigned short*)alloc((size_t)512 * 64 * 2);
    unsigned short* Wp4 = (unsigned short*)alloc((size_t)1024 * 32 * 2);
    (void)ws_size; (void)in_sizes; (void)n_in; (void)out_size;

    // --- prologue ---
    pack_all_kernel<<<640, 256, 0, stream>>>(W1, W2, W3, W4, Wp1, Wp2, Wp3, Wp4);
    hipMemsetAsync(cnt, 0, (size_t)NPTS * sizeof(int), stream);
    hist_kernel<<<(NEDGE + 1023) / 1024, 256, 0, stream>>>(rel_pos, receivers, ws_ptr, cnt, rank);
    scan_kernel<<<1, 1024, 0, stream>>>(cnt, rowptr);
    fill_kernel<<<(NEDGE + 1023) / 1024, 256, 0, stream>>>(rel_pos, receivers, senders, ws_ptr,
                                                           rowptr, rank, ec);
    build_xab_kernel<<<(NPTS * 64 + 255) / 256, 256, 0, stream>>>(x, y, xab);

    // Layer 1
    fused_layer<64, 64><<<NPTS / 8, 256, 0, stream>>>(xab, ec, rowptr, Wp1, a, P1, part);
    bn_mid_kernel<64><<<64, 256, 0, stream>>>(part, part2);
    bn_fin_kernel<64><<<1, 1024, 0, stream>>>(part2, g1, b1, scb);
    apply_relu_bf16_kernel<64><<<(NPTS * 64 + 255) / 256, 256, 0, stream>>>(P1, scb, fb64);

    // Layer 2
    fused_layer<64, 32><<<NPTS / 8, 256, 0, stream>>>(fb64, ec, rowptr, Wp2, a, P2, part);
    bn_mid_kernel<32><<<64, 256, 0, stream>>>(part, part2);
    bn_fin_kernel<32><<<1, 1024, 0, stream>>>(part2, g2, b2, scb);
    apply_sigmix_bf16_kernel<<<(NPTS * 32 + 255) / 256, 256, 0, stream>>>(P2, scb, x, y, xob);

    // Layer 3
    fused_layer<32, 64><<<NPTS / 8, 256, 0, stream>>>(xob, ec, rowptr, Wp3, a, P1, part);
    bn_mid_kernel<64><<<64, 256, 0, stream>>>(part, part2);
    bn_fin_kernel<64><<<1, 1024, 0, stream>>>(part2, g3, b3, scb);
    apply_relu_bf16_kernel<64><<<(NPTS * 64 + 255) / 256, 256, 0, stream>>>(P1, scb, fb64);

    // Layer 4
    fused_layer<64, 32><<<NPTS / 8, 256, 0, stream>>>(fb64, ec, rowptr, Wp4, a, P2, part);
    bn_mid_kernel<32><<<64, 256, 0, stream>>>(part, part2);
    bn_fin_kernel<32><<<1, 1024, 0, stream>>>(part2, g4, b4, scb);
    apply_sigmix_kernel<<<(NPTS * 32 + 255) / 256, 256, 0, stream>>>(P2, scb, x, y, (float*)d_out);
}

// Round 28
// 234.388 us; speedup vs baseline: 1.0433x; 1.0433x over previous
//
#include <hip/hip_runtime.h>

#define NPTS 40000
#define NEDGE 1000000
#define BN_EPS 1e-5f

typedef short bf16x8 __attribute__((ext_vector_type(8)));
typedef float f32x4 __attribute__((ext_vector_type(4)));

__device__ __forceinline__ unsigned short f2bf(float x) {
    unsigned u = __float_as_uint(x);
    return (unsigned short)((u + 0x7FFFu + ((u >> 16) & 1u)) >> 16);  // RTN-even
}
__device__ __forceinline__ bf16x8 pack8(unsigned v0, unsigned v1, unsigned v2, unsigned v3,
                                        unsigned v4, unsigned v5, unsigned v6, unsigned v7) {
    uint4 u = make_uint4(v0 | (v1 << 16), v2 | (v3 << 16), v4 | (v5 << 16), v6 | (v7 << 16));
    return __builtin_bit_cast(bf16x8, u);
}

// ===========================================================================
// Edge geometry: validity + cell + corner weights (w00,w01,w10,w11).
// ===========================================================================
__device__ inline bool edge_geom(const float* rel_pos, const int* ws_ptr, int e,
                                 int& cell, float4& w4) {
    float ws = (float)ws_ptr[0];
    float inv_ws = 1.0f / ws;
    float ux = rel_pos[2 * e] * inv_ws;
    float uy = rel_pos[2 * e + 1] * inv_ws;
    float q = 1.0f - (ux * ux + uy * uy);
    if (!(q > 0.0f)) return false;
    float win = q * q * q;
    float gx = fminf(fmaxf((ux + 1.0f) * 1.5f, 0.0f), 3.0f);
    float gy = fminf(fmaxf((uy + 1.0f) * 1.5f, 0.0f), 3.0f);
    int ix = (int)floorf(gx); ix = ix < 0 ? 0 : (ix > 2 ? 2 : ix);
    int iy = (int)floorf(gy); iy = iy < 0 ? 0 : (iy > 2 ? 2 : iy);
    float fx = gx - (float)ix;
    float fy = gy - (float)iy;
    cell = ix * 4 + iy;
    float wx0 = (1.f - fx) * win, wx1 = fx * win;
    float wy0 = 1.f - fy, wy1 = fy;
    w4 = make_float4(wx0 * wy0, wx0 * wy1, wx1 * wy0, wx1 * wy1);
    return true;
}

// hist captures each edge's rank (atomicAdd return) so fill is atomic-free.
__global__ void hist_kernel(const float* __restrict__ rel_pos,
                            const int* __restrict__ receivers,
                            const int* __restrict__ ws_ptr,
                            int* __restrict__ cnt,
                            int* __restrict__ rank) {
    int base = blockIdx.x * 1024 + threadIdx.x;
#pragma unroll
    for (int i = 0; i < 4; ++i) {
        int e = base + i * 256;
        if (e >= NEDGE) continue;
        int cell; float4 w4;
        int r = -1;
        if (edge_geom(rel_pos, ws_ptr, e, cell, w4))
            r = atomicAdd(&cnt[receivers[e]], 1);
        rank[e] = r;
    }
}

// one block, 1024 threads: exclusive scan of 40000 counts -> rowptr[40001]
__global__ __launch_bounds__(1024) void scan_kernel(const int* __restrict__ cnt,
                                                    int* __restrict__ rowptr) {
    __shared__ int part[1024];
    int t = threadIdx.x;
    const int CHUNK = 40;
    int base = t * CHUNK;
    int s = 0;
    if (t < 1000)
        for (int i = 0; i < CHUNK; ++i) s += cnt[base + i];
    part[t] = s;
    __syncthreads();
    for (int off = 1; off < 1024; off <<= 1) {
        int v = (t >= off) ? part[t - off] : 0;
        __syncthreads();
        part[t] += v;
        __syncthreads();
    }
    int excl = (t == 0) ? 0 : part[t - 1];
    if (t < 1000) {
        int run = excl;
        for (int i = 0; i < CHUNK; ++i) { rowptr[base + i] = run; run += cnt[base + i]; }
        if (t == 999) rowptr[NPTS] = run;
    }
}

// Edge record 16B: {sender | cell<<16, bf16(w00)|bf16(w01)<<16,
//                   bf16(w10)|bf16(w11)<<16, 0}; atomic-free via rank[].
__global__ void fill_kernel(const float* __restrict__ rel_pos,
                            const int* __restrict__ receivers,
                            const int* __restrict__ senders,
                            const int* __restrict__ ws_ptr,
                            const int* __restrict__ rowptr,
                            const int* __restrict__ rank,
                            uint4* __restrict__ ec) {
    int base = blockIdx.x * 1024 + threadIdx.x;
#pragma unroll
    for (int i = 0; i < 4; ++i) {
        int e = base + i * 256;
        if (e >= NEDGE) continue;
        int r = rank[e];
        if (r < 0) continue;
        int cell; float4 w4;
        edge_geom(rel_pos, ws_ptr, e, cell, w4);   // valid by construction
        int pos = rowptr[receivers[e]] + r;
        unsigned meta = (unsigned)senders[e] | ((unsigned)cell << 16);
        unsigned wlo = (unsigned)f2bf(w4.x) | ((unsigned)f2bf(w4.y) << 16);
        unsigned whi = (unsigned)f2bf(w4.z) | ((unsigned)f2bf(w4.w) << 16);
        ec[pos] = make_uint4(meta, wlo, whi, 0u);
    }
}

// ===========================================================================
// Merged W repack into bf16 MFMA B-fragment layout.
// ===========================================================================
__global__ void pack_all_kernel(const float* __restrict__ W1, const float* __restrict__ W2,
                                const float* __restrict__ W3, const float* __restrict__ W4,
                                unsigned short* __restrict__ Wp1, unsigned short* __restrict__ Wp2,
                                unsigned short* __restrict__ Wp3, unsigned short* __restrict__ Wp4) {
    int idx = blockIdx.x * 256 + threadIdx.x;
    const float* W; unsigned short* Wp; int M, COUT, base;
    if (idx < 65536)       { W = W1; Wp = Wp1; M = 1024; COUT = 64; base = 0; }
    else if (idx < 98304)  { W = W2; Wp = Wp2; M = 1024; COUT = 32; base = 65536; }
    else if (idx < 131072) { W = W3; Wp = Wp3; M = 512;  COUT = 64; base = 98304; }
    else if (idx < 163840) { W = W4; Wp = Wp4; M = 1024; COUT = 32; base = 131072; }
    else return;
    int i = idx - base;
    int nKS = M / 32;
    int j = i & 7, l = (i >> 3) & 63, t = i >> 9;
    int ks = t % nKS, cb = t / nKS;
    int m = ks * 32 + (l >> 4) * 8 + j;
    int col = cb * 16 + (l & 15);
    Wp[i] = f2bf(W[(size_t)m * COUT + col]);
}

// bf16 concat(x,y) -> xab[N][64]
__global__ void build_xab_kernel(const float* __restrict__ x,
                                 const float* __restrict__ y,
                                 unsigned short* __restrict__ xab) {
    int t = blockIdx.x * blockDim.x + threadIdx.x;
    if (t >= NPTS * 64) return;
    int n = t >> 6, c = t & 63;
    xab[t] = f2bf((c < 32) ? x[n * 32 + c] : y[n * 32 + (c - 32)]);
}

// ===========================================================================
// Fused cconv layer, MFMA scatter + MFMA GEMM (r24 measured-best: LDS-staged
// records + permuted colblocks -> one NCB-wide feature load per edge).
// Terminal diagnosis: phase 1 is VMEM-request-throughput bound (invariant
// across occupancy 32%/64%, ILP shape, staging scheme) — ~50M 8B gather
// requests/layer is intrinsic to the per-edge feature gather.
// ===========================================================================
template <int CIN, int COUT>
__global__ __launch_bounds__(256, 4) void fused_layer(const unsigned short* __restrict__ featb,
                                                      const uint4* __restrict__ ec,
                                                      const int* __restrict__ rowptr,
                                                      const unsigned short* __restrict__ Wp,
                                                      const float* __restrict__ a,
                                                      float* __restrict__ P,
                                                      float* __restrict__ part) {
    constexpr int RB = 16;
    constexpr int M = 16 * CIN;
    constexpr int LDB = M + 8;
    constexpr int nKS = M / 32;
    constexpr int NCB = CIN / 16;
    constexpr int CT = COUT / 16;
    __shared__ short S_bf[RB * LDB];
    __shared__ uint4 stage[4][32];
    __shared__ float Rred[CT == 2 ? 512 : 4];

    int tid = threadIdx.x;
    int lane = tid & 63;
    int wave = tid >> 6;
    int col = lane & 15;
    int kgrp = lane >> 4;
    int rcx = col >> 2, rcy = col & 3;

    for (int r = 0; r < 4; ++r) {
        int rloc = wave * 4 + r;
        int rglob = blockIdx.x * RB + rloc;
        int rs = rowptr[rglob];
        int deg = rowptr[rglob + 1] - rs;

        f32x4 acc[NCB];
#pragma unroll
        for (int cb = 0; cb < NCB; ++cb) acc[cb] = f32x4{0.f, 0.f, 0.f, 0.f};

        for (int c0 = 0; c0 < deg; c0 += 32) {
            if (lane < 32) {
                uint4 rec = (c0 + lane < deg) ? ec[rs + c0 + lane]
                                              : make_uint4(0u, 0u, 0u, 0u);
                stage[wave][lane] = rec;
            }
            unsigned aw[8];
            uint2 fv4[8];
            unsigned fv2[8];
#pragma unroll
            for (int j = 0; j < 8; ++j) {
                uint4 rec = stage[wave][kgrp * 8 + j];
                int cell = (int)(rec.x >> 16);
                int ix = cell >> 2, iy = cell & 3;
                unsigned pair = (rcx == ix) ? rec.y : rec.z;
                unsigned half = (rcy == iy) ? (pair & 0xFFFFu) : (pair >> 16);
                bool vx = (rcx == ix) || (rcx == ix + 1);
                bool vy = (rcy == iy) || (rcy == iy + 1);
                aw[j] = (vx && vy) ? half : 0u;
                int sb = (int)(rec.x & 0xFFFFu) * CIN + col * NCB;
                if constexpr (NCB == 4)
                    fv4[j] = *(const uint2*)&featb[sb];
                else
                    fv2[j] = *(const unsigned*)&featb[sb];
            }
            bf16x8 afrag = pack8(aw[0], aw[1], aw[2], aw[3], aw[4], aw[5], aw[6], aw[7]);
            if constexpr (NCB == 4) {
                bf16x8 b0 = pack8(fv4[0].x & 0xFFFFu, fv4[1].x & 0xFFFFu, fv4[2].x & 0xFFFFu,
                                  fv4[3].x & 0xFFFFu, fv4[4].x & 0xFFFFu, fv4[5].x & 0xFFFFu,
                                  fv4[6].x & 0xFFFFu, fv4[7].x & 0xFFFFu);
                bf16x8 b1 = pack8(fv4[0].x >> 16, fv4[1].x >> 16, fv4[2].x >> 16, fv4[3].x >> 16,
                                  fv4[4].x >> 16, fv4[5].x >> 16, fv4[6].x >> 16, fv4[7].x >> 16);
                bf16x8 b2 = pack8(fv4[0].y & 0xFFFFu, fv4[1].y & 0xFFFFu, fv4[2].y & 0xFFFFu,
                                  fv4[3].y & 0xFFFFu, fv4[4].y & 0xFFFFu, fv4[5].y & 0xFFFFu,
                                  fv4[6].y & 0xFFFFu, fv4[7].y & 0xFFFFu);
                bf16x8 b3 = pack8(fv4[0].y >> 16, fv4[1].y >> 16, fv4[2].y >> 16, fv4[3].y >> 16,
                                  fv4[4].y >> 16, fv4[5].y >> 16, fv4[6].y >> 16, fv4[7].y >> 16);
                acc[0] = __builtin_amdgcn_mfma_f32_16x16x32_bf16(afrag, b0, acc[0], 0, 0, 0);
                acc[1] = __builtin_amdgcn_mfma_f32_16x16x32_bf16(afrag, b1, acc[1], 0, 0, 0);
                acc[2] = __builtin_amdgcn_mfma_f32_16x16x32_bf16(afrag, b2, acc[2], 0, 0, 0);
                acc[3] = __builtin_amdgcn_mfma_f32_16x16x32_bf16(afrag, b3, acc[3], 0, 0, 0);
            } else {
                bf16x8 b0 = pack8(fv2[0] & 0xFFFFu, fv2[1] & 0xFFFFu, fv2[2] & 0xFFFFu,
                                  fv2[3] & 0xFFFFu, fv2[4] & 0xFFFFu, fv2[5] & 0xFFFFu,
                                  fv2[6] & 0xFFFFu, fv2[7] & 0xFFFFu);
                bf16x8 b1 = pack8(fv2[0] >> 16, fv2[1] >> 16, fv2[2] >> 16, fv2[3] >> 16,
                                  fv2[4] >> 16, fv2[5] >> 16, fv2[6] >> 16, fv2[7] >> 16);
                acc[0] = __builtin_amdgcn_mfma_f32_16x16x32_bf16(afrag, b0, acc[0], 0, 0, 0);
                acc[1] = __builtin_amdgcn_mfma_f32_16x16x32_bf16(afrag, b1, acc[1], 0, 0, 0);
            }
        }

        // epilogue: unpermute -> S_bf[cell][channel], channel = col*NCB + cb
        short* srow = &S_bf[rloc * LDB];
#pragma unroll
        for (int i = 0; i < 4; ++i) {
            if constexpr (NCB == 4) {
                unsigned lo = (unsigned)f2bf(acc[0][i]) | ((unsigned)f2bf(acc[1][i]) << 16);
                unsigned hi = (unsigned)f2bf(acc[2][i]) | ((unsigned)f2bf(acc[3][i]) << 16);
                *(uint2*)&srow[(kgrp * 4 + i) * CIN + col * 4] = make_uint2(lo, hi);
            } else {
                unsigned lo = (unsigned)f2bf(acc[0][i]) | ((unsigned)f2bf(acc[1][i]) << 16);
                *(unsigned*)&srow[(kgrp * 4 + i) * CIN + col * 2] = lo;
            }
        }
    }
    __syncthreads();

    // --- phase 2: MFMA GEMM ---
    int row16 = lane & 15;
    f32x4 c = {0.f, 0.f, 0.f, 0.f};
    int cb, ks0;
    constexpr int KS_PER = (CT == 4) ? nKS : nKS / 2;
    if constexpr (CT == 4) { cb = wave; ks0 = 0; }
    else { cb = wave & 1; ks0 = (wave >> 1) * KS_PER; }

    const short* abase = &S_bf[row16 * LDB + kgrp * 8];
    const bf16x8* wfrag = (const bf16x8*)Wp;
    size_t wbase = (size_t)(cb * nKS + ks0) * 64 + lane;
#pragma unroll 8
    for (int kk = 0; kk < KS_PER; ++kk) {
        bf16x8 af = *(const bf16x8*)(abase + (size_t)(ks0 + kk) * 32);
        bf16x8 bf = wfrag[wbase + (size_t)kk * 64];
        c = __builtin_amdgcn_mfma_f32_16x16x32_bf16(af, bf, c, 0, 0, 0);
    }

    if constexpr (CT == 2) {
        if (wave >= 2) {
#pragma unroll
            for (int i = 0; i < 4; ++i)
                Rred[cb * 256 + (kgrp * 4 + i) * 16 + row16] = c[i];
        }
        __syncthreads();
        if (wave < 2) {
            float sp = 0.f, sq = 0.f;
#pragma unroll
            for (int i = 0; i < 4; ++i) {
                int row = kgrp * 4 + i;
                int n = blockIdx.x * RB + row;
                float v = a[n] * (c[i] + Rred[cb * 256 + row * 16 + row16]);
                P[(size_t)n * COUT + cb * 16 + row16] = v;
                sp += v; sq += v * v;
            }
            sp += __shfl_xor(sp, 16); sp += __shfl_xor(sp, 32);
            sq += __shfl_xor(sq, 16); sq += __shfl_xor(sq, 32);
            if (kgrp == 0) {
                part[(size_t)blockIdx.x * 2 * COUT + cb * 16 + row16] = sp;
                part[(size_t)blockIdx.x * 2 * COUT + COUT + cb * 16 + row16] = sq;
            }
        }
    } else {
        float sp = 0.f, sq = 0.f;
#pragma unroll
        for (int i = 0; i < 4; ++i) {
            int row = kgrp * 4 + i;
            int n = blockIdx.x * RB + row;
            float v = a[n] * c[i];
            P[(size_t)n * COUT + cb * 16 + row16] = v;
            sp += v; sq += v * v;
        }
        sp += __shfl_xor(sp, 16); sp += __shfl_xor(sp, 32);
        sq += __shfl_xor(sq, 16); sq += __shfl_xor(sq, 32);
        if (kgrp == 0) {
            part[(size_t)blockIdx.x * 2 * COUT + cb * 16 + row16] = sp;
            part[(size_t)blockIdx.x * 2 * COUT + COUT + cb * 16 + row16] = sq;
        }
    }
}

// ===========================================================================
// BN reduction (static trip counts; NB = NPTS/16 = 2500 partial rows).
// ===========================================================================
template <int COUT>
__global__ __launch_bounds__(256) void bn_mid_kernel(const float* __restrict__ part,
                                                     float* __restrict__ part2) {
    constexpr int C2 = 2 * COUT;
    constexpr int NG = 256 / C2;
    constexpr int NB = NPTS / 16;
    constexpr int NRB = (NB + 63) / 64;
    __shared__ float ls[256];
    int tid = threadIdx.x;
    int d = tid % C2;
    int gi = tid / C2;
    int k0 = blockIdx.x * NRB;
    float s = 0.f;
#pragma unroll
    for (int j = 0; j < NRB / NG + 1; ++j) {
        int k = k0 + gi + j * NG;
        bool ok = (gi + j * NG < NRB) && (k < NB);
        s += ok ? part[(size_t)k * C2 + d] : 0.f;
    }
    ls[tid] = s;
    __syncthreads();
    if (gi == 0) {
        float tot = s;
#pragma unroll
        for (int g2 = 1; g2 < NG; ++g2) tot += ls[tid + g2 * C2];
        part2[(size_t)blockIdx.x * C2 + d] = tot;
    }
}

template <int COUT>
__global__ __launch_bounds__(1024) void bn_fin_kernel(const float* __restrict__ part2,
                                                      const float* __restrict__ g,
                                                      const float* __restrict__ b,
                                                      float* __restrict__ scb) {
    constexpr int C2 = 2 * COUT;
    constexpr int NG = 1024 / C2;
    __shared__ float ls[1024];
    int tid = threadIdx.x;
    int d = tid % C2;
    int gi = tid / C2;
    float s = 0.f;
#pragma unroll
    for (int j = 0; j < 64 / NG; ++j)
        s += part2[(size_t)(gi + j * NG) * C2 + d];
    ls[tid] = s;
    __syncthreads();
    if (tid < C2) {
        float tot = ls[tid];
#pragma unroll
        for (int g2 = 1; g2 < NG; ++g2) tot += ls[tid + g2 * C2];
        ls[tid] = tot;
    }
    __syncthreads();
    if (tid < COUT) {
        float sum = ls[tid], ssq = ls[COUT + tid];
        float mean = sum / (float)NPTS;
        float var = ssq / (float)NPTS - mean * mean;
        float inv = rsqrtf(var + BN_EPS);
        float scale = inv * g[tid];
        scb[tid] = scale;
        scb[COUT + tid] = b[tid] - mean * scale;
    }
}

// relu(bn(P)) -> bf16 feature buffer
template <int COUT>
__global__ void apply_relu_bf16_kernel(const float* __restrict__ P,
                                       const float* __restrict__ scb,
                                       unsigned short* __restrict__ fb) {
    int t = blockIdx.x * blockDim.x + threadIdx.x;
    if (t >= NPTS * COUT) return;
    int d = t % COUT;
    float v = P[t] * scb[d] + scb[COUT + d];
    fb[t] = f2bf(fmaxf(v, 0.0f));
}

// sigmoid-mix -> bf16 feature buffer
__global__ void apply_sigmix_bf16_kernel(const float* __restrict__ P,
                                         const float* __restrict__ scb,
                                         const float* __restrict__ x,
                                         const float* __restrict__ y,
                                         unsigned short* __restrict__ xob) {
    int t = blockIdx.x * blockDim.x + threadIdx.x;
    if (t >= NPTS * 32) return;
    int d = t & 31;
    float v = P[t] * scb[d] + scb[32 + d];
    float w = 1.0f / (1.0f + expf(-v));
    xob[t] = f2bf(2.0f * x[t] * w + 2.0f * y[t] * (1.0f - w));
}

// final sigmoid-mix -> f32 output
__global__ void apply_sigmix_kernel(const float* __restrict__ P,
                                    const float* __restrict__ scb,
                                    const float* __restrict__ x,
                                    const float* __restrict__ y,
                                    float* __restrict__ out) {
    int t = blockIdx.x * blockDim.x + threadIdx.x;
    if (t >= NPTS * 32) return;
    int d = t & 31;
    float v = P[t] * scb[d] + scb[32 + d];
    float w = 1.0f / (1.0f + expf(-v));
    out[t] = 2.0f * x[t] * w + 2.0f * y[t] * (1.0f - w);
}

extern "C" void kernel_launch(void* const* d_in, const int* in_sizes, int n_in,
                              void* d_out, int out_size, void* d_ws, size_t ws_size,
                              hipStream_t stream) {
    const float* x = (const float*)d_in[0];
    const float* y = (const float*)d_in[1];
    const int* senders = (const int*)d_in[2];
    const int* receivers = (const int*)d_in[3];
    const float* rel_pos = (const float*)d_in[4];
    const int* ws_ptr = (const int*)d_in[5];
    const float* a = (const float*)d_in[6];
    const float* W1 = (const float*)d_in[7];
    const float* W2 = (const float*)d_in[8];
    const float* W3 = (const float*)d_in[9];
    const float* W4 = (const float*)d_in[10];
    const float* g1 = (const float*)d_in[11];
    const float* b1 = (const float*)d_in[12];
    const float* g2 = (const float*)d_in[13];
    const float* b2 = (const float*)d_in[14];
    const float* g3 = (const float*)d_in[15];
    const float* b3 = (const float*)d_in[16];
    const float* g4 = (const float*)d_in[17];
    const float* b4 = (const float*)d_in[18];

    char* ws = (char*)d_ws;
    size_t off = 0;
    auto alloc = [&](size_t bytes) -> void* {
        void* p = ws + off;
        off += (bytes + 255) & ~(size_t)255;
        return p;
    };
    int* cnt = (int*)alloc((size_t)NPTS * sizeof(int));
    int* rowptr = (int*)alloc((size_t)(NPTS + 1) * sizeof(int));
    int* rank = (int*)alloc((size_t)NEDGE * sizeof(int));
    uint4* ec = (uint4*)alloc((size_t)(NEDGE + 4) * sizeof(uint4));
    unsigned short* xab = (unsigned short*)alloc((size_t)NPTS * 64 * 2);
    unsigned short* fb64 = (unsigned short*)alloc((size_t)NPTS * 64 * 2);
    unsigned short* xob = (unsigned short*)alloc((size_t)NPTS * 32 * 2);
    float* P1 = (float*)alloc((size_t)NPTS * 64 * sizeof(float));  // also P3
    float* P2 = (float*)alloc((size_t)NPTS * 32 * sizeof(float));  // also P4
    float* part = (float*)alloc((size_t)(NPTS / 16) * 128 * sizeof(float));
    float* part2 = (float*)alloc((size_t)64 * 128 * sizeof(float));
    float* scb = (float*)alloc(2 * 64 * sizeof(float));
    unsigned short* Wp1 = (unsigned short*)alloc((size_t)1024 * 64 * 2);
    unsigned short* Wp2 = (unsigned short*)alloc((size_t)1024 * 32 * 2);
    unsigned short* Wp3 = (unsigned short*)alloc((size_t)512 * 64 * 2);
    unsigned short* Wp4 = (unsigned short*)alloc((size_t)1024 * 32 * 2);
    (void)ws_size; (void)in_sizes; (void)n_in; (void)out_size;

    // --- prologue ---
    pack_all_kernel<<<640, 256, 0, stream>>>(W1, W2, W3, W4, Wp1, Wp2, Wp3, Wp4);
    hipMemsetAsync(cnt, 0, (size_t)NPTS * sizeof(int), stream);
    hist_kernel<<<(NEDGE + 1023) / 1024, 256, 0, stream>>>(rel_pos, receivers, ws_ptr, cnt, rank);
    scan_kernel<<<1, 1024, 0, stream>>>(cnt, rowptr);
    fill_kernel<<<(NEDGE + 1023) / 1024, 256, 0, stream>>>(rel_pos, receivers, senders, ws_ptr,
                                                           rowptr, rank, ec);
    build_xab_kernel<<<(NPTS * 64 + 255) / 256, 256, 0, stream>>>(x, y, xab);

    // Layer 1
    fused_layer<64, 64><<<NPTS / 16, 256, 0, stream>>>(xab, ec, rowptr, Wp1, a, P1, part);
    bn_mid_kernel<64><<<64, 256, 0, stream>>>(part, part2);
    bn_fin_kernel<64><<<1, 1024, 0, stream>>>(part2, g1, b1, scb);
    apply_relu_bf16_kernel<64><<<(NPTS * 64 + 255) / 256, 256, 0, stream>>>(P1, scb, fb64);

    // Layer 2
    fused_layer<64, 32><<<NPTS / 16, 256, 0, stream>>>(fb64, ec, rowptr, Wp2, a, P2, part);
    bn_mid_kernel<32><<<64, 256, 0, stream>>>(part, part2);
    bn_fin_kernel<32><<<1, 1024, 0, stream>>>(part2, g2, b2, scb);
    apply_sigmix_bf16_kernel<<<(NPTS * 32 + 255) / 256, 256, 0, stream>>>(P2, scb, x, y, xob);

    // Layer 3
    fused_layer<32, 64><<<NPTS / 16, 256, 0, stream>>>(xob, ec, rowptr, Wp3, a, P1, part);
    bn_mid_kernel<64><<<64, 256, 0, stream>>>(part, part2);
    bn_fin_kernel<64><<<1, 1024, 0, stream>>>(part2, g3, b3, scb);
    apply_relu_bf16_kernel<64><<<(NPTS * 64 + 255) / 256, 256, 0, stream>>>(P1, scb, fb64);

    // Layer 4
    fused_layer<64, 32><<<NPTS / 16, 256, 0, stream>>>(fb64, ec, rowptr, Wp4, a, P2, part);
    bn_mid_kernel<32><<<64, 256, 0, stream>>>(part, part2);
    bn_fin_kernel<32><<<1, 1024, 0, stream>>>(part2, g4, b4, scb);
    apply_sigmix_kernel<<<(NPTS * 32 + 255) / 256, 256, 0, stream>>>(P2, scb, x, y, (float*)d_out);
}